// Round 8
// baseline (2182.886 us; speedup 1.0000x reference)
//
#include <hip/hip_runtime.h>
#include <stdint.h>

// WeightOnlyInt4Linear: y = X @ dequant(Q)^T ; M=8192, K=4096, N=11008, G=128.
// Round 8: one-phase-ahead read pipeline. MMA order (0,0)->(1,0)->(0,1)->(1,1);
// each phase ISSUES the reads consumed by the NEXT phase, so the LDS pipe runs
// under the MFMA pipe by program order. P3/P4 prefetch next tile's Ah0/Bh0 into
// the just-dead a0/b0 registers. Sync: mid VMW(4)+BAR, end VMW(2)+BAR.

typedef __attribute__((ext_vector_type(8))) short short8;
typedef __attribute__((ext_vector_type(4))) float float4v;
typedef __attribute__((ext_vector_type(4))) int int4v;
typedef __attribute__((ext_vector_type(2))) float float2v;
typedef __attribute__((ext_vector_type(4))) unsigned short ushort4v;

static constexpr int M_ = 8192;
static constexpr int K_ = 4096;
static constexpr int N_ = 11008;
static constexpr int NKT = K_ / 64;  // 64 K-tiles

__device__ __forceinline__ unsigned short f2bf(float f) {
    union { float f; uint32_t u; } v;
    v.f = f;
    uint32_t u = v.u;
    u += 0x7fffu + ((u >> 16) & 1u);  // RNE
    return (unsigned short)(u >> 16);
}

__device__ __forceinline__ void gload16(const void* g, void* l) {
    __builtin_amdgcn_global_load_lds(
        (const __attribute__((address_space(1))) uint32_t*)g,
        (__attribute__((address_space(3))) uint32_t*)l, 16, 0, 0);
}

// ---------------- Prepass 1: X fp32 -> bf16 ----------------
__global__ __launch_bounds__(256) void cvt_x_kernel(const float* __restrict__ X,
                                                    unsigned short* __restrict__ Xb) {
    const int i = blockIdx.x * 256 + threadIdx.x;
    const float4v a = ((const float4v*)X)[2 * (size_t)i];
    const float4v b = ((const float4v*)X)[2 * (size_t)i + 1];
    short8 o;
    #pragma unroll
    for (int j = 0; j < 4; ++j) o[j] = (short)f2bf(a[j]);
    #pragma unroll
    for (int j = 0; j < 4; ++j) o[4 + j] = (short)f2bf(b[j]);
    ((short8*)Xb)[(size_t)i] = o;
}

// ---------------- Prepass 2: W int4 codes -> bf16 ----------------
__global__ __launch_bounds__(256) void deq_w_kernel(const int* __restrict__ Q,
                                                    const float* __restrict__ SZ,
                                                    unsigned short* __restrict__ Wb) {
    const int i = blockIdx.x * 256 + threadIdx.x;  // < N*K/8
    const int n = i >> 9;
    const int c = i & 511;
    const int k0 = c * 8;
    const int g = k0 >> 7;
    const float2v sz = *(const float2v*)(SZ + ((size_t)g * N_ + n) * 2);
    const float s = sz[0], z = sz[1];
    const int4v q0 = *(const int4v*)(Q + (size_t)n * K_ + k0);
    const int4v q1 = *(const int4v*)(Q + (size_t)n * K_ + k0 + 4);
    short8 o;
    #pragma unroll
    for (int j = 0; j < 4; ++j) o[j] = (short)f2bf((float)(q0[j] - 8) * s + z);
    #pragma unroll
    for (int j = 0; j < 4; ++j) o[4 + j] = (short)f2bf((float)(q1[j] - 8) * s + z);
    ((short8*)Wb)[(size_t)i] = o;
}

// ---------------- 256x256 GEMM, pipelined reads ----------------
// LDS (bytes): A buf0 [0,32K) A buf1 [32K,64K) B buf0 [64K,96K) B buf1 [96K,128K)
// Tile: 256 rows x 64 bf16 (128 B/row); half = 128 rows = 16 KB.
// Swizzle: phys_col_byte = logical_col_byte ^ ((row&7)<<4).

template <int BUF, int MH>
__device__ __forceinline__ void read_a(const char* ldsB, short8 (&a)[4][2],
                                       int aRB, int k0o, int k1o) {
    const int abase = BUF * 32768 + MH * 16384 + aRB;
    #pragma unroll
    for (int i = 0; i < 4; ++i) {
        a[i][0] = *(const short8*)(ldsB + abase + i * 2048 + k0o);
        a[i][1] = *(const short8*)(ldsB + abase + i * 2048 + k1o);
    }
}

template <int BUF, int NH>
__device__ __forceinline__ void read_b(const char* ldsB, short8 (&b)[2][2],
                                       int bRB, int k0o, int k1o) {
    const int bbase = 65536 + BUF * 32768 + NH * 16384 + bRB;
    #pragma unroll
    for (int j = 0; j < 2; ++j) {
        b[j][0] = *(const short8*)(ldsB + bbase + j * 2048 + k0o);
        b[j][1] = *(const short8*)(ldsB + bbase + j * 2048 + k1o);
    }
}

template <int MH, int NH>
__device__ __forceinline__ void phase_mma(short8 (&a)[4][2], short8 (&b)[2][2],
                                          float4v (&acc)[8][4]) {
    __builtin_amdgcn_s_setprio(1);
    #pragma unroll
    for (int i = 0; i < 4; ++i)
        #pragma unroll
        for (int j = 0; j < 2; ++j) {
            acc[MH * 4 + i][NH * 2 + j] = __builtin_amdgcn_mfma_f32_16x16x32_bf16(
                a[i][0], b[j][0], acc[MH * 4 + i][NH * 2 + j], 0, 0, 0);
            acc[MH * 4 + i][NH * 2 + j] = __builtin_amdgcn_mfma_f32_16x16x32_bf16(
                a[i][1], b[j][1], acc[MH * 4 + i][NH * 2 + j], 0, 0, 0);
        }
    __builtin_amdgcn_s_setprio(0);
}

#define SBAR() __builtin_amdgcn_sched_barrier(0)
#define VMW(n) asm volatile("s_waitcnt vmcnt(" #n ")" ::: "memory")

__global__ __launch_bounds__(512, 2) void gemm_bf16_8ph(
    const unsigned short* __restrict__ Agl,  // [M][K] bf16
    const unsigned short* __restrict__ Bgl,  // [N][K] bf16
    float* __restrict__ C) {
    __shared__ alignas(16) unsigned short lds[65536];  // 128 KiB

    const int tid = threadIdx.x;
    const int lane = tid & 63;
    const int wid = tid >> 6;   // 0..7
    const int wr = wid >> 2;    // 0..1 (M sub-block within half)
    const int wc = wid & 3;     // 0..3 (N sub-block within half)

    // T1: XCD swizzle over 1376 = 8*172 blocks.
    const int bid = blockIdx.x;
    const int wg = (bid & 7) * 172 + (bid >> 3);
    const int mt = wg / 43;
    const int nt = wg % 43;
    const int row0 = mt * 256;
    const int col0 = nt * 256;

    // staging lane geometry: wave writes 8 rows x 128 B linear; lane's row&7 = lane>>3.
    const int r8 = lane >> 3;                // 0..7 == row&7
    const int kc = ((lane & 7) ^ r8) * 8;    // inverse-swizzled global k-elem offset

    // ds_read lane geometry: read row&7 = l15&7 (other row terms are mult of 16).
    const int l15 = lane & 15;
    const int k0o = ((lane >> 4) * 16) ^ ((l15 & 7) << 4);
    const int k1o = k0o ^ 64;  // bit6 XOR commutes with the row XOR on bits[6:4]
    const int aRB = (wr * 64 + l15) * 128;
    const int bRB = (wc * 32 + l15) * 128;
    const char* ldsB = (const char*)lds;
    unsigned short* ldsU = lds;

    auto stageA = [&](int kt, int b, int h) {
        #pragma unroll
        for (int i = 0; i < 2; ++i) {
            const int rbase = h * 128 + (wid * 2 + i) * 8;
            gload16(Agl + (size_t)(row0 + rbase + r8) * K_ + kt * 64 + kc,
                    ldsU + b * 16384 + rbase * 64);
        }
    };
    auto stageB = [&](int kt, int b, int h) {
        #pragma unroll
        for (int i = 0; i < 2; ++i) {
            const int rbase = h * 128 + (wid * 2 + i) * 8;
            gload16(Bgl + (size_t)(col0 + rbase + r8) * K_ + kt * 64 + kc,
                    ldsU + 32768 + b * 16384 + rbase * 64);
        }
    };

    float4v acc[8][4] = {};
    short8 a0[4][2], a1[4][2];  // A h0 / h1 fragments
    short8 b0[2][2], b1[2][2];  // B h0 / h1 fragments

    // Prologue: tile 0 (buf0) fully + A(1,h0) into buf1; leave A(1,h0) in flight.
    stageA(0, 0, 0); stageA(0, 0, 1); stageB(0, 0, 0); stageB(0, 0, 1);
    stageA(1, 1, 0);
    VMW(2);
    __builtin_amdgcn_s_barrier();
    SBAR();
    read_a<0, 0>(ldsB, a0, aRB, k0o, k1o);
    read_b<0, 0>(ldsB, b0, bRB, k0o, k1o);

    int t;
    // Per-tile schedule (BUF = t&1). Entry: a0=Ah0(t), b0=Bh0(t) in regs;
    //   in flight: S3(t-1)=A(t+1,h0)->BUF^1 [2 loads].
    // P1: read Ah1(t)            ; stage S1={A(t+1,h1),B(t+1,h0)}->BUF^1 ; mma(0,0)=a0*b0
    // P2: read Bh1(t)            ; stage S2={B(t+1,h1)}->BUF^1           ; mma(1,0)=a1*b0
    // mid: stage S3={A(t+2,h0)}->BUF ; VMW(4) drains S3(t-1)+S1 ; BAR
    // P3: read Bh0(t+1)<-BUF^1   ; mma(0,1)=a0*b1   (a0 dead after)
    // P4: read Ah0(t+1)<-BUF^1   ; mma(1,1)=a1*b1
    // end: VMW(2) drains S2 ; BAR.  Queue 10->4->2 steady state.
#define KTILE(BUF, DN, DN2, MIDW, ENDW)                                    \
    {                                                                      \
        read_a<BUF, 1>(ldsB, a1, aRB, k0o, k1o);                           \
        if (DN) { stageA(t + 1, (BUF) ^ 1, 1); stageB(t + 1, (BUF) ^ 1, 0); } \
        phase_mma<0, 0>(a0, b0, acc);                                      \
        read_b<BUF, 1>(ldsB, b1, bRB, k0o, k1o);                           \
        if (DN) stageB(t + 1, (BUF) ^ 1, 1);                               \
        phase_mma<1, 0>(a1, b0, acc);                                      \
        if (DN2) stageA(t + 2, BUF, 0);                                    \
        if (DN) {                                                          \
            SBAR(); VMW(MIDW);                                             \
            __builtin_amdgcn_s_barrier(); SBAR();                          \
            read_b<(BUF) ^ 1, 0>(ldsB, b0, bRB, k0o, k1o);                 \
        }                                                                  \
        phase_mma<0, 1>(a0, b1, acc);                                      \
        if (DN) read_a<(BUF) ^ 1, 0>(ldsB, a0, aRB, k0o, k1o);             \
        phase_mma<1, 1>(a1, b1, acc);                                      \
        if (DN) {                                                          \
            SBAR(); VMW(ENDW);                                             \
            __builtin_amdgcn_s_barrier(); SBAR();                          \
        }                                                                  \
    }

    for (int t2 = 0; t2 < NKT - 2; t2 += 2) {
        t = t2;     KTILE(0, 1, 1, 4, 2);
        t = t2 + 1; KTILE(1, 1, 1, 4, 2);
    }
    t = NKT - 2; KTILE(0, 1, 0, 2, 0);  // no S3; mid drains S3(61)+S1; end drains S2
    t = NKT - 1; KTILE(1, 0, 0, 0, 0);  // no stages, no prefetch reads, no syncs
#undef KTILE

    // Epilogue: D map col=lane&15, row=(lane>>4)*4+j (m89-verified).
    const int lrow = (lane >> 4) * 4;
    #pragma unroll
    for (int mf = 0; mf < 8; ++mf)
        #pragma unroll
        for (int nf = 0; nf < 4; ++nf)
            #pragma unroll
            for (int j = 0; j < 4; ++j) {
                const int r = row0 + (mf >> 2) * 128 + wr * 64 + (mf & 3) * 16 + lrow + j;
                const int c = col0 + (nf >> 1) * 128 + wc * 32 + (nf & 1) * 16 + l15;
                C[(size_t)r * N_ + c] = acc[mf][nf][j];
            }
}

// ---------------- Fallback: round-1 fused kernel ----------------
static constexpr int LDSS = 40;

__global__ __launch_bounds__(256, 2) void w4_gemm_fused(
    const float* __restrict__ X, const int* __restrict__ Q,
    const float* __restrict__ SZ, float* __restrict__ C) {
    __shared__ alignas(16) unsigned short As[128 * LDSS];
    __shared__ alignas(16) unsigned short Ws[128 * LDSS];
    const int tid = threadIdx.x;
    const int lane = tid & 63;
    const int wid = tid >> 6;
    const int wrr = wid >> 1;
    const int wcc = wid & 1;
    const int row0 = blockIdx.x * 128;
    const int col0 = blockIdx.y * 128;
    float4v acc[4][4] = {};
    float4v a_reg[4];
    int4v q_reg[4];
    float2v sz_reg[4];

    auto load_tile = [&](int kb) {
        const int g = kb >> 7;
        #pragma unroll
        for (int i = 0; i < 4; ++i) {
            const int idx = tid + 256 * i;
            const int r = idx >> 3;
            const int v = idx & 7;
            a_reg[i] = *(const float4v*)(X + (size_t)(row0 + r) * K_ + kb + v * 4);
            q_reg[i] = *(const int4v*)(Q + (size_t)(col0 + r) * K_ + kb + v * 4);
            sz_reg[i] = *(const float2v*)(SZ + ((size_t)g * N_ + (col0 + r)) * 2);
        }
    };
    auto write_tile = [&]() {
        #pragma unroll
        for (int i = 0; i < 4; ++i) {
            const int idx = tid + 256 * i;
            const int r = idx >> 3;
            const int v = idx & 7;
            ushort4v ab, wb;
            #pragma unroll
            for (int j = 0; j < 4; ++j) ab[j] = f2bf(a_reg[i][j]);
            const float s = sz_reg[i][0];
            const float z = sz_reg[i][1];
            #pragma unroll
            for (int j = 0; j < 4; ++j) wb[j] = f2bf((float)(q_reg[i][j] - 8) * s + z);
            *(ushort4v*)(&As[r * LDSS + v * 4]) = ab;
            *(ushort4v*)(&Ws[r * LDSS + v * 4]) = wb;
        }
    };
    auto compute = [&]() {
        const int lr = lane & 15;
        const int lg = lane >> 4;
        short8 af[4], bf[4];
        #pragma unroll
        for (int mf = 0; mf < 4; ++mf)
            af[mf] = *(const short8*)(&As[(wrr * 64 + mf * 16 + lr) * LDSS + lg * 8]);
        #pragma unroll
        for (int nf = 0; nf < 4; ++nf)
            bf[nf] = *(const short8*)(&Ws[(wcc * 64 + nf * 16 + lr) * LDSS + lg * 8]);
        #pragma unroll
        for (int mf = 0; mf < 4; ++mf)
            #pragma unroll
            for (int nf = 0; nf < 4; ++nf)
                acc[mf][nf] = __builtin_amdgcn_mfma_f32_16x16x32_bf16(
                    af[mf], bf[nf], acc[mf][nf], 0, 0, 0);
    };

    load_tile(0);
    for (int kb = 0; kb < K_; kb += 32) {
        __syncthreads();
        write_tile();
        __syncthreads();
        if (kb + 32 < K_) load_tile(kb + 32);
        compute();
    }
    const int lr = lane & 15;
    const int lg = lane >> 4;
    #pragma unroll
    for (int mf = 0; mf < 4; ++mf)
        #pragma unroll
        for (int nf = 0; nf < 4; ++nf)
            #pragma unroll
            for (int j = 0; j < 4; ++j) {
                const int r = row0 + wrr * 64 + mf * 16 + lg * 4 + j;
                const int c = col0 + wcc * 64 + nf * 16 + lr;
                C[(size_t)r * N_ + c] = acc[mf][nf][j];
            }
}

extern "C" void kernel_launch(void* const* d_in, const int* in_sizes, int n_in,
                              void* d_out, int out_size, void* d_ws, size_t ws_size,
                              hipStream_t stream) {
    const float* X  = (const float*)d_in[0];
    const int*   Q  = (const int*)d_in[1];
    const float* SZ = (const float*)d_in[2];
    float* C = (float*)d_out;

    const size_t xb_bytes = (size_t)M_ * K_ * 2;
    const size_t wb_bytes = (size_t)N_ * K_ * 2;
    if (ws_size >= xb_bytes + wb_bytes) {
        unsigned short* Xb = (unsigned short*)d_ws;
        unsigned short* Wb = (unsigned short*)((char*)d_ws + xb_bytes);
        cvt_x_kernel<<<(M_ * (K_ / 8)) / 256, 256, 0, stream>>>(X, Xb);
        deq_w_kernel<<<(N_ * (K_ / 8)) / 256, 256, 0, stream>>>(Q, SZ, Wb);
        gemm_bf16_8ph<<<dim3(1376), dim3(512), 0, stream>>>(Xb, Wb, C);
    } else {
        dim3 grid(M_ / 128, N_ / 128);
        w4_gemm_fused<<<grid, dim3(256), 0, stream>>>(X, Q, SZ, C);
    }
}

// Round 9
// 802.539 us; speedup vs baseline: 2.7200x; 2.7200x over previous
//
#include <hip/hip_runtime.h>
#include <stdint.h>

// WeightOnlyInt4Linear: y = X @ dequant(Q)^T ; M=8192, K=4096, N=11008, G=128.
// Round 9: round-8 one-phase-ahead pipeline (proven correct) + register relief:
//  - 8 persistent 32-bit staging offsets (self-advancing +128 B/tile), no 64-bit
//    address recomputation inside SBAR-pinned regions;
//  - 4 loop-invariant ds_read base regs; all ds offsets are 16-bit immediates
//    (B bases pre-biased by +65536).
// Round-8 spill signature was WRITE_SIZE 353MB -> 1.66GB; this must revert it.

typedef __attribute__((ext_vector_type(8))) short short8;
typedef __attribute__((ext_vector_type(4))) float float4v;
typedef __attribute__((ext_vector_type(4))) int int4v;
typedef __attribute__((ext_vector_type(2))) float float2v;
typedef __attribute__((ext_vector_type(4))) unsigned short ushort4v;

static constexpr int M_ = 8192;
static constexpr int K_ = 4096;
static constexpr int N_ = 11008;
static constexpr int NKT = K_ / 64;  // 64 K-tiles

__device__ __forceinline__ unsigned short f2bf(float f) {
    union { float f; uint32_t u; } v;
    v.f = f;
    uint32_t u = v.u;
    u += 0x7fffu + ((u >> 16) & 1u);  // RNE
    return (unsigned short)(u >> 16);
}

__device__ __forceinline__ void gload16(const void* g, void* l) {
    __builtin_amdgcn_global_load_lds(
        (const __attribute__((address_space(1))) uint32_t*)g,
        (__attribute__((address_space(3))) uint32_t*)l, 16, 0, 0);
}

// ---------------- Prepass 1: X fp32 -> bf16 ----------------
__global__ __launch_bounds__(256) void cvt_x_kernel(const float* __restrict__ X,
                                                    unsigned short* __restrict__ Xb) {
    const int i = blockIdx.x * 256 + threadIdx.x;
    const float4v a = ((const float4v*)X)[2 * (size_t)i];
    const float4v b = ((const float4v*)X)[2 * (size_t)i + 1];
    short8 o;
    #pragma unroll
    for (int j = 0; j < 4; ++j) o[j] = (short)f2bf(a[j]);
    #pragma unroll
    for (int j = 0; j < 4; ++j) o[4 + j] = (short)f2bf(b[j]);
    ((short8*)Xb)[(size_t)i] = o;
}

// ---------------- Prepass 2: W int4 codes -> bf16 ----------------
__global__ __launch_bounds__(256) void deq_w_kernel(const int* __restrict__ Q,
                                                    const float* __restrict__ SZ,
                                                    unsigned short* __restrict__ Wb) {
    const int i = blockIdx.x * 256 + threadIdx.x;  // < N*K/8
    const int n = i >> 9;
    const int c = i & 511;
    const int k0 = c * 8;
    const int g = k0 >> 7;
    const float2v sz = *(const float2v*)(SZ + ((size_t)g * N_ + n) * 2);
    const float s = sz[0], z = sz[1];
    const int4v q0 = *(const int4v*)(Q + (size_t)n * K_ + k0);
    const int4v q1 = *(const int4v*)(Q + (size_t)n * K_ + k0 + 4);
    short8 o;
    #pragma unroll
    for (int j = 0; j < 4; ++j) o[j] = (short)f2bf((float)(q0[j] - 8) * s + z);
    #pragma unroll
    for (int j = 0; j < 4; ++j) o[4 + j] = (short)f2bf((float)(q1[j] - 8) * s + z);
    ((short8*)Wb)[(size_t)i] = o;
}

// ---------------- 256x256 GEMM, one-phase-ahead pipeline ----------------
// LDS (bytes): A buf0 [0,32K) A buf1 [32K,64K) B buf0 [64K,96K) B buf1 [96K,128K)
// Tile: 256 rows x 64 bf16 (128 B/row); half = 128 rows = 16 KB.
// Swizzle: phys_col_byte = logical_col_byte ^ ((row&7)<<4).

template <int BUF, int MH>
__device__ __forceinline__ void read_a(const char* ldsB, short8 (&a)[4][2],
                                       int aK0, int aK1) {
    constexpr int base = BUF * 32768 + MH * 16384;
    #pragma unroll
    for (int i = 0; i < 4; ++i) {
        a[i][0] = *(const short8*)(ldsB + base + i * 2048 + aK0);
        a[i][1] = *(const short8*)(ldsB + base + i * 2048 + aK1);
    }
}

template <int BUF, int NH>
__device__ __forceinline__ void read_b(const char* ldsB, short8 (&b)[2][2],
                                       int bK0, int bK1) {
    constexpr int base = BUF * 32768 + NH * 16384;  // bK* carry the +65536 bias
    #pragma unroll
    for (int j = 0; j < 2; ++j) {
        b[j][0] = *(const short8*)(ldsB + base + j * 2048 + bK0);
        b[j][1] = *(const short8*)(ldsB + base + j * 2048 + bK1);
    }
}

template <int MH, int NH>
__device__ __forceinline__ void phase_mma(short8 (&a)[4][2], short8 (&b)[2][2],
                                          float4v (&acc)[8][4]) {
    __builtin_amdgcn_s_setprio(1);
    #pragma unroll
    for (int i = 0; i < 4; ++i)
        #pragma unroll
        for (int j = 0; j < 2; ++j) {
            acc[MH * 4 + i][NH * 2 + j] = __builtin_amdgcn_mfma_f32_16x16x32_bf16(
                a[i][0], b[j][0], acc[MH * 4 + i][NH * 2 + j], 0, 0, 0);
            acc[MH * 4 + i][NH * 2 + j] = __builtin_amdgcn_mfma_f32_16x16x32_bf16(
                a[i][1], b[j][1], acc[MH * 4 + i][NH * 2 + j], 0, 0, 0);
        }
    __builtin_amdgcn_s_setprio(0);
}

#define SBAR() __builtin_amdgcn_sched_barrier(0)
#define VMW(n) asm volatile("s_waitcnt vmcnt(" #n ")" ::: "memory")

__global__ __launch_bounds__(512, 2) void gemm_bf16_8ph(
    const unsigned short* __restrict__ Agl,  // [M][K] bf16
    const unsigned short* __restrict__ Bgl,  // [N][K] bf16
    float* __restrict__ C) {
    __shared__ alignas(16) unsigned short lds[65536];  // 128 KiB

    const int tid = threadIdx.x;
    const int lane = tid & 63;
    const int wid = tid >> 6;   // 0..7
    const int wr = wid >> 2;    // 0..1 (M sub-block within half)
    const int wc = wid & 3;     // 0..3 (N sub-block within half)

    // T1: XCD swizzle over 1376 = 8*172 blocks.
    const int bid = blockIdx.x;
    const int wg = (bid & 7) * 172 + (bid >> 3);
    const int mt = wg / 43;
    const int nt = wg % 43;
    const int row0 = mt * 256;
    const int col0 = nt * 256;

    // staging lane geometry: wave writes 8 rows x 128 B linear; lane's row&7 = lane>>3.
    const int r8 = lane >> 3;                // 0..7 == row&7
    const int kc = ((lane & 7) ^ r8) * 8;    // inverse-swizzled global k-elem offset

    // ds_read lane geometry: read row&7 = l15&7 (other row terms are mult of 16).
    const int l15 = lane & 15;
    const int k0o = ((lane >> 4) * 16) ^ ((l15 & 7) << 4);
    const int k1o = k0o ^ 64;  // bit6 XOR commutes with the row XOR on bits[6:4]
    const int aK0 = (wr * 64 + l15) * 128 + k0o;          // A ds_read bases
    const int aK1 = (wr * 64 + l15) * 128 + k1o;
    const int bK0 = 65536 + (wc * 32 + l15) * 128 + k0o;  // B bases (+64K bias)
    const int bK1 = 65536 + (wc * 32 + l15) * 128 + k1o;
    const char* ldsB = (const char*)lds;
    unsigned short* ldsU = lds;
    const char* AglB = (const char*)Agl;
    const char* BglB = (const char*)Bgl;

    // Persistent 32-bit staging byte-offsets, one per stream [h][i].
    // Each advances +128 B after use; lookahead is baked in by use order.
    uint32_t sA[2][2], sB[2][2];
    #pragma unroll
    for (int h = 0; h < 2; ++h)
        #pragma unroll
        for (int i = 0; i < 2; ++i) {
            sA[h][i] = (uint32_t)(row0 + h * 128 + (wid * 2 + i) * 8 + r8) * (K_ * 2)
                       + (uint32_t)kc * 2;
            sB[h][i] = (uint32_t)(col0 + h * 128 + (wid * 2 + i) * 8 + r8) * (K_ * 2)
                       + (uint32_t)kc * 2;
        }

    auto gA = [&](uint32_t& off, int b, int h, int i) {
        gload16(AglB + off, ldsU + b * 16384 + (h * 128 + (wid * 2 + i) * 8) * 64);
        off += 128;
    };
    auto gB = [&](uint32_t& off, int b, int h, int i) {
        gload16(BglB + off, ldsU + 32768 + b * 16384 + (h * 128 + (wid * 2 + i) * 8) * 64);
        off += 128;
    };

    float4v acc[8][4] = {};
    short8 a0[4][2], a1[4][2];  // A h0 / h1 fragments
    short8 b0[2][2], b1[2][2];  // B h0 / h1 fragments

    // Prologue: tile 0 (buf0) fully + A(1,h0) into buf1; leave A(1,h0) in flight.
    gA(sA[0][0], 0, 0, 0); gA(sA[0][1], 0, 0, 1);   // A(0,h0)
    gA(sA[1][0], 0, 1, 0); gA(sA[1][1], 0, 1, 1);   // A(0,h1)
    gB(sB[0][0], 0, 0, 0); gB(sB[0][1], 0, 0, 1);   // B(0,h0)
    gB(sB[1][0], 0, 1, 0); gB(sB[1][1], 0, 1, 1);   // B(0,h1)
    gA(sA[0][0], 1, 0, 0); gA(sA[0][1], 1, 0, 1);   // A(1,h0) -> buf1
    VMW(2);
    __builtin_amdgcn_s_barrier();
    SBAR();
    read_a<0, 0>(ldsB, a0, aK0, aK1);
    read_b<0, 0>(ldsB, b0, bK0, bK1);
    // Streams now point at: sA[0]=t2, sA[1]=t1, sB[0]=t1, sB[1]=t1. Steady state.

    // Per-tile schedule (BUF = t&1). Entry: a0=Ah0(t), b0=Bh0(t) in regs;
    //   in flight: S3(t-1)=A(t+1,h0)->BUF^1 [2 loads].
    // P1: read Ah1(t)          ; stage S1={A(t+1,h1),B(t+1,h0)}->BUF^1 ; mma(0,0)
    // P2: read Bh1(t)          ; stage S2={B(t+1,h1)}->BUF^1           ; mma(1,0)
    // mid: stage S3={A(t+2,h0)}->BUF ; VMW(4) drains S3(t-1)+S1 ; BAR
    // P3: read Bh0(t+1)<-BUF^1 ; mma(0,1)
    // P4: read Ah0(t+1)<-BUF^1 ; mma(1,1)
    // end: VMW(2) drains S2 ; BAR.  Queue 10->4->2 steady state.
#define KTILE(BUF, DN, DN2, MIDW, ENDW)                                    \
    {                                                                      \
        read_a<BUF, 1>(ldsB, a1, aK0, aK1);                                \
        if (DN) {                                                          \
            gA(sA[1][0], (BUF) ^ 1, 1, 0); gA(sA[1][1], (BUF) ^ 1, 1, 1);  \
            gB(sB[0][0], (BUF) ^ 1, 0, 0); gB(sB[0][1], (BUF) ^ 1, 0, 1);  \
        }                                                                  \
        phase_mma<0, 0>(a0, b0, acc);                                      \
        read_b<BUF, 1>(ldsB, b1, bK0, bK1);                                \
        if (DN) { gB(sB[1][0], (BUF) ^ 1, 1, 0); gB(sB[1][1], (BUF) ^ 1, 1, 1); } \
        phase_mma<1, 0>(a1, b0, acc);                                      \
        if (DN2) { gA(sA[0][0], BUF, 0, 0); gA(sA[0][1], BUF, 0, 1); }     \
        if (DN) {                                                          \
            SBAR(); VMW(MIDW);                                             \
            __builtin_amdgcn_s_barrier(); SBAR();                          \
            read_b<(BUF) ^ 1, 0>(ldsB, b0, bK0, bK1);                      \
        }                                                                  \
        phase_mma<0, 1>(a0, b1, acc);                                      \
        if (DN) read_a<(BUF) ^ 1, 0>(ldsB, a0, aK0, aK1);                  \
        phase_mma<1, 1>(a1, b1, acc);                                      \
        if (DN) {                                                          \
            SBAR(); VMW(ENDW);                                             \
            __builtin_amdgcn_s_barrier(); SBAR();                          \
        }                                                                  \
    }

    for (int t2 = 0; t2 < NKT - 2; t2 += 2) {
        KTILE(0, 1, 1, 4, 2);
        KTILE(1, 1, 1, 4, 2);
    }
    KTILE(0, 1, 0, 2, 0);  // t=NKT-2: no S3; mid drains old S3+S1; end drains S2
    KTILE(1, 0, 0, 0, 0);  // t=NKT-1: no stages, no prefetch reads, no syncs
#undef KTILE

    // Epilogue: D map col=lane&15, row=(lane>>4)*4+j (m89-verified).
    const int lrow = (lane >> 4) * 4;
    #pragma unroll
    for (int mf = 0; mf < 8; ++mf)
        #pragma unroll
        for (int nf = 0; nf < 4; ++nf)
            #pragma unroll
            for (int j = 0; j < 4; ++j) {
                const int r = row0 + (mf >> 2) * 128 + wr * 64 + (mf & 3) * 16 + lrow + j;
                const int c = col0 + (nf >> 1) * 128 + wc * 32 + (nf & 1) * 16 + l15;
                C[(size_t)r * N_ + c] = acc[mf][nf][j];
            }
}

// ---------------- Fallback: round-1 fused kernel ----------------
static constexpr int LDSS = 40;

__global__ __launch_bounds__(256, 2) void w4_gemm_fused(
    const float* __restrict__ X, const int* __restrict__ Q,
    const float* __restrict__ SZ, float* __restrict__ C) {
    __shared__ alignas(16) unsigned short As[128 * LDSS];
    __shared__ alignas(16) unsigned short Ws[128 * LDSS];
    const int tid = threadIdx.x;
    const int lane = tid & 63;
    const int wid = tid >> 6;
    const int wrr = wid >> 1;
    const int wcc = wid & 1;
    const int row0 = blockIdx.x * 128;
    const int col0 = blockIdx.y * 128;
    float4v acc[4][4] = {};
    float4v a_reg[4];
    int4v q_reg[4];
    float2v sz_reg[4];

    auto load_tile = [&](int kb) {
        const int g = kb >> 7;
        #pragma unroll
        for (int i = 0; i < 4; ++i) {
            const int idx = tid + 256 * i;
            const int r = idx >> 3;
            const int v = idx & 7;
            a_reg[i] = *(const float4v*)(X + (size_t)(row0 + r) * K_ + kb + v * 4);
            q_reg[i] = *(const int4v*)(Q + (size_t)(col0 + r) * K_ + kb + v * 4);
            sz_reg[i] = *(const float2v*)(SZ + ((size_t)g * N_ + (col0 + r)) * 2);
        }
    };
    auto write_tile = [&]() {
        #pragma unroll
        for (int i = 0; i < 4; ++i) {
            const int idx = tid + 256 * i;
            const int r = idx >> 3;
            const int v = idx & 7;
            ushort4v ab, wb;
            #pragma unroll
            for (int j = 0; j < 4; ++j) ab[j] = f2bf(a_reg[i][j]);
            const float s = sz_reg[i][0];
            const float z = sz_reg[i][1];
            #pragma unroll
            for (int j = 0; j < 4; ++j) wb[j] = f2bf((float)(q_reg[i][j] - 8) * s + z);
            *(ushort4v*)(&As[r * LDSS + v * 4]) = ab;
            *(ushort4v*)(&Ws[r * LDSS + v * 4]) = wb;
        }
    };
    auto compute = [&]() {
        const int lr = lane & 15;
        const int lg = lane >> 4;
        short8 af[4], bf[4];
        #pragma unroll
        for (int mf = 0; mf < 4; ++mf)
            af[mf] = *(const short8*)(&As[(wrr * 64 + mf * 16 + lr) * LDSS + lg * 8]);
        #pragma unroll
        for (int nf = 0; nf < 4; ++nf)
            bf[nf] = *(const short8*)(&Ws[(wcc * 64 + nf * 16 + lr) * LDSS + lg * 8]);
        #pragma unroll
        for (int mf = 0; mf < 4; ++mf)
            #pragma unroll
            for (int nf = 0; nf < 4; ++nf)
                acc[mf][nf] = __builtin_amdgcn_mfma_f32_16x16x32_bf16(
                    af[mf], bf[nf], acc[mf][nf], 0, 0, 0);
    };

    load_tile(0);
    for (int kb = 0; kb < K_; kb += 32) {
        __syncthreads();
        write_tile();
        __syncthreads();
        if (kb + 32 < K_) load_tile(kb + 32);
        compute();
    }
    const int lr = lane & 15;
    const int lg = lane >> 4;
    #pragma unroll
    for (int mf = 0; mf < 4; ++mf)
        #pragma unroll
        for (int nf = 0; nf < 4; ++nf)
            #pragma unroll
            for (int j = 0; j < 4; ++j) {
                const int r = row0 + wrr * 64 + mf * 16 + lg * 4 + j;
                const int c = col0 + wcc * 64 + nf * 16 + lr;
                C[(size_t)r * N_ + c] = acc[mf][nf][j];
            }
}

extern "C" void kernel_launch(void* const* d_in, const int* in_sizes, int n_in,
                              void* d_out, int out_size, void* d_ws, size_t ws_size,
                              hipStream_t stream) {
    const float* X  = (const float*)d_in[0];
    const int*   Q  = (const int*)d_in[1];
    const float* SZ = (const float*)d_in[2];
    float* C = (float*)d_out;

    const size_t xb_bytes = (size_t)M_ * K_ * 2;
    const size_t wb_bytes = (size_t)N_ * K_ * 2;
    if (ws_size >= xb_bytes + wb_bytes) {
        unsigned short* Xb = (unsigned short*)d_ws;
        unsigned short* Wb = (unsigned short*)((char*)d_ws + xb_bytes);
        cvt_x_kernel<<<(M_ * (K_ / 8)) / 256, 256, 0, stream>>>(X, Xb);
        deq_w_kernel<<<(N_ * (K_ / 8)) / 256, 256, 0, stream>>>(Q, SZ, Wb);
        gemm_bf16_8ph<<<dim3(1376), dim3(512), 0, stream>>>(Xb, Wb, C);
    } else {
        dim3 grid(M_ / 128, N_ / 128);
        w4_gemm_fused<<<grid, dim3(256), 0, stream>>>(X, Q, SZ, C);
    }
}

// Round 10
// 750.445 us; speedup vs baseline: 2.9088x; 1.0694x over previous
//
#include <hip/hip_runtime.h>
#include <stdint.h>

// WeightOnlyInt4Linear: y = X @ dequant(Q)^T ; M=8192, K=4096, N=11008, G=128.
// Round 10: m201-faithful phase cadence. Per K-tile, 4 phases of
//   {ds_reads ; stage 2 gloads->BUF^1 ; BAR ; lgkmcnt(0)+schedbar ; 16 MFMA ;
//    counted VMW ; BAR}
// Overlap mechanism: phase P's read burst runs while phase P-1's MFMA batch
// drains the matrix pipe (barrier cadence aligns them CU-wide).
// Stages all target BUF^1 (A0',B0',B1',A1' at P1..P4) -> no same-buf hazard.
// Per-wave vmcnt ring: steady 4 -> 6 -> VMW(4) at P1/P2/P4 ends; tail 2/0.

typedef __attribute__((ext_vector_type(8))) short short8;
typedef __attribute__((ext_vector_type(4))) float float4v;
typedef __attribute__((ext_vector_type(4))) int int4v;
typedef __attribute__((ext_vector_type(2))) float float2v;
typedef __attribute__((ext_vector_type(4))) unsigned short ushort4v;

static constexpr int M_ = 8192;
static constexpr int K_ = 4096;
static constexpr int N_ = 11008;
static constexpr int NKT = K_ / 64;  // 64 K-tiles

__device__ __forceinline__ unsigned short f2bf(float f) {
    union { float f; uint32_t u; } v;
    v.f = f;
    uint32_t u = v.u;
    u += 0x7fffu + ((u >> 16) & 1u);  // RNE
    return (unsigned short)(u >> 16);
}

__device__ __forceinline__ void gload16(const void* g, void* l) {
    __builtin_amdgcn_global_load_lds(
        (const __attribute__((address_space(1))) uint32_t*)g,
        (__attribute__((address_space(3))) uint32_t*)l, 16, 0, 0);
}

// ---------------- Prepass 1: X fp32 -> bf16 ----------------
__global__ __launch_bounds__(256) void cvt_x_kernel(const float* __restrict__ X,
                                                    unsigned short* __restrict__ Xb) {
    const int i = blockIdx.x * 256 + threadIdx.x;
    const float4v a = ((const float4v*)X)[2 * (size_t)i];
    const float4v b = ((const float4v*)X)[2 * (size_t)i + 1];
    short8 o;
    #pragma unroll
    for (int j = 0; j < 4; ++j) o[j] = (short)f2bf(a[j]);
    #pragma unroll
    for (int j = 0; j < 4; ++j) o[4 + j] = (short)f2bf(b[j]);
    ((short8*)Xb)[(size_t)i] = o;
}

// ---------------- Prepass 2: W int4 codes -> bf16 ----------------
__global__ __launch_bounds__(256) void deq_w_kernel(const int* __restrict__ Q,
                                                    const float* __restrict__ SZ,
                                                    unsigned short* __restrict__ Wb) {
    const int i = blockIdx.x * 256 + threadIdx.x;  // < N*K/8
    const int n = i >> 9;
    const int c = i & 511;
    const int k0 = c * 8;
    const int g = k0 >> 7;
    const float2v sz = *(const float2v*)(SZ + ((size_t)g * N_ + n) * 2);
    const float s = sz[0], z = sz[1];
    const int4v q0 = *(const int4v*)(Q + (size_t)n * K_ + k0);
    const int4v q1 = *(const int4v*)(Q + (size_t)n * K_ + k0 + 4);
    short8 o;
    #pragma unroll
    for (int j = 0; j < 4; ++j) o[j] = (short)f2bf((float)(q0[j] - 8) * s + z);
    #pragma unroll
    for (int j = 0; j < 4; ++j) o[4 + j] = (short)f2bf((float)(q1[j] - 8) * s + z);
    ((short8*)Wb)[(size_t)i] = o;
}

// ---------------- 256x256 GEMM, m201 cadence ----------------
// LDS (bytes): A buf0 [0,32K) A buf1 [32K,64K) B buf0 [64K,96K) B buf1 [96K,128K)
// Tile: 256 rows x 64 bf16 (128 B/row); half = 128 rows = 16 KB.
// Swizzle: phys_col_byte = logical_col_byte ^ ((row&7)<<4).

template <int BUF, int MH>
__device__ __forceinline__ void read_a(const char* ldsB, short8 (&a)[4][2],
                                       int aK0, int aK1) {
    constexpr int base = BUF * 32768 + MH * 16384;
    #pragma unroll
    for (int i = 0; i < 4; ++i) {
        a[i][0] = *(const short8*)(ldsB + base + i * 2048 + aK0);
        a[i][1] = *(const short8*)(ldsB + base + i * 2048 + aK1);
    }
}

template <int BUF, int NH>
__device__ __forceinline__ void read_b(const char* ldsB, short8 (&b)[2][2],
                                       int bK0, int bK1) {
    constexpr int base = BUF * 32768 + NH * 16384;  // bK* carry the +65536 bias
    #pragma unroll
    for (int j = 0; j < 2; ++j) {
        b[j][0] = *(const short8*)(ldsB + base + j * 2048 + bK0);
        b[j][1] = *(const short8*)(ldsB + base + j * 2048 + bK1);
    }
}

template <int MH, int NH>
__device__ __forceinline__ void phase_mma(short8 (&a)[4][2], short8 (&b)[2][2],
                                          float4v (&acc)[8][4]) {
    __builtin_amdgcn_s_setprio(1);
    #pragma unroll
    for (int i = 0; i < 4; ++i)
        #pragma unroll
        for (int j = 0; j < 2; ++j) {
            acc[MH * 4 + i][NH * 2 + j] = __builtin_amdgcn_mfma_f32_16x16x32_bf16(
                a[i][0], b[j][0], acc[MH * 4 + i][NH * 2 + j], 0, 0, 0);
            acc[MH * 4 + i][NH * 2 + j] = __builtin_amdgcn_mfma_f32_16x16x32_bf16(
                a[i][1], b[j][1], acc[MH * 4 + i][NH * 2 + j], 0, 0, 0);
        }
    __builtin_amdgcn_s_setprio(0);
}

#define SBAR() __builtin_amdgcn_sched_barrier(0)
#define VMW(n) asm volatile("s_waitcnt vmcnt(" #n ")" ::: "memory")
#define LGKM(n) asm volatile("s_waitcnt lgkmcnt(" #n ")" ::: "memory")
#define BARRIER() __builtin_amdgcn_s_barrier()

__global__ __launch_bounds__(512, 2) void gemm_bf16_8ph(
    const unsigned short* __restrict__ Agl,  // [M][K] bf16
    const unsigned short* __restrict__ Bgl,  // [N][K] bf16
    float* __restrict__ C) {
    __shared__ alignas(16) unsigned short lds[65536];  // 128 KiB

    const int tid = threadIdx.x;
    const int lane = tid & 63;
    const int wid = tid >> 6;   // 0..7
    const int wr = wid >> 2;    // 0..1 (M sub-block within half)
    const int wc = wid & 3;     // 0..3 (N sub-block within half)

    // T1: XCD swizzle over 1376 = 8*172 blocks.
    const int bid = blockIdx.x;
    const int wg = (bid & 7) * 172 + (bid >> 3);
    const int mt = wg / 43;
    const int nt = wg % 43;
    const int row0 = mt * 256;
    const int col0 = nt * 256;

    // staging lane geometry: wave writes 8 rows x 128 B linear; lane's row&7 = lane>>3.
    const int r8 = lane >> 3;                // 0..7 == row&7
    const int kc = ((lane & 7) ^ r8) * 8;    // inverse-swizzled global k-elem offset

    // ds_read lane geometry: read row&7 = l15&7 (other row terms are mult of 16).
    const int l15 = lane & 15;
    const int k0o = ((lane >> 4) * 16) ^ ((l15 & 7) << 4);
    const int k1o = k0o ^ 64;  // bit6 XOR commutes with the row XOR on bits[6:4]
    const int aK0 = (wr * 64 + l15) * 128 + k0o;          // A ds_read bases
    const int aK1 = (wr * 64 + l15) * 128 + k1o;
    const int bK0 = 65536 + (wc * 32 + l15) * 128 + k0o;  // B bases (+64K bias)
    const int bK1 = 65536 + (wc * 32 + l15) * 128 + k1o;
    const char* ldsB = (const char*)lds;
    unsigned short* ldsU = lds;
    const char* AglB = (const char*)Agl;
    const char* BglB = (const char*)Bgl;

    // Persistent 32-bit staging byte-offsets, one per stream [h][i]; +128 B/use.
    uint32_t sA[2][2], sB[2][2];
    #pragma unroll
    for (int h = 0; h < 2; ++h)
        #pragma unroll
        for (int i = 0; i < 2; ++i) {
            sA[h][i] = (uint32_t)(row0 + h * 128 + (wid * 2 + i) * 8 + r8) * (K_ * 2)
                       + (uint32_t)kc * 2;
            sB[h][i] = (uint32_t)(col0 + h * 128 + (wid * 2 + i) * 8 + r8) * (K_ * 2)
                       + (uint32_t)kc * 2;
        }

    auto gA = [&](uint32_t& off, int b, int h, int i) {
        gload16(AglB + off, ldsU + b * 16384 + (h * 128 + (wid * 2 + i) * 8) * 64);
        off += 128;
    };
    auto gB = [&](uint32_t& off, int b, int h, int i) {
        gload16(BglB + off, ldsU + 32768 + b * 16384 + (h * 128 + (wid * 2 + i) * 8) * 64);
        off += 128;
    };

    float4v acc[8][4] = {};

    // Prologue: stage tile 0 -> buf0, issue order [A0, B0, B1, A1] (2 loads each).
    // VMW(4) drains A0,B0 (needed by tile-0 P1 reads); B1,A1 stay in flight.
    gA(sA[0][0], 0, 0, 0); gA(sA[0][1], 0, 0, 1);
    gB(sB[0][0], 0, 0, 0); gB(sB[0][1], 0, 0, 1);
    gB(sB[1][0], 0, 1, 0); gB(sB[1][1], 0, 1, 1);
    gA(sA[1][0], 0, 1, 0); gA(sA[1][1], 0, 1, 1);
    VMW(4);
    BARRIER(); SBAR();

    // Per tile (BUF): phases P1..P4; stages (if DN) go to BUF^1 in order
    // A0',B0',B1',A1'. Per-wave vmcnt: entry 4 {B1,A1}; P1-end 6 -> VMW(W1)
    // drains B1 (P2 reads it); P2-end 6 -> VMW(W2) drains A1 (P3 reads);
    // P4-end 8 -> VMW(W3) drains A0',B0' (next P1 reads). Steady W=4; tail 2/0.
#define KTILE(BUF, DN, W1, W2, W3, DOEND)                                   \
    {                                                                       \
        short8 a0[4][2], a1[4][2], b0[2][2], b1[2][2];                      \
        /* P1: read A0,B0 (12) ; stage A0(t+1) */                           \
        read_a<BUF, 0>(ldsB, a0, aK0, aK1);                                 \
        read_b<BUF, 0>(ldsB, b0, bK0, bK1);                                 \
        if (DN) { gA(sA[0][0], (BUF) ^ 1, 0, 0); gA(sA[0][1], (BUF) ^ 1, 0, 1); } \
        LGKM(8);                                                            \
        BARRIER(); SBAR();                                                  \
        LGKM(0); SBAR();                                                    \
        phase_mma<0, 0>(a0, b0, acc);                                       \
        VMW(W1);                                                            \
        BARRIER(); SBAR();                                                  \
        /* P2: read B1 (4) ; stage B0(t+1) */                               \
        read_b<BUF, 1>(ldsB, b1, bK0, bK1);                                 \
        if (DN) { gB(sB[0][0], (BUF) ^ 1, 0, 0); gB(sB[0][1], (BUF) ^ 1, 0, 1); } \
        BARRIER(); SBAR();                                                  \
        LGKM(0); SBAR();                                                    \
        phase_mma<0, 1>(a0, b1, acc);                                       \
        VMW(W2);                                                            \
        BARRIER(); SBAR();                                                  \
        /* P3: read A1 (8) ; stage B1(t+1) */                               \
        read_a<BUF, 1>(ldsB, a1, aK0, aK1);                                 \
        if (DN) { gB(sB[1][0], (BUF) ^ 1, 1, 0); gB(sB[1][1], (BUF) ^ 1, 1, 1); } \
        BARRIER(); SBAR();                                                  \
        LGKM(0); SBAR();                                                    \
        phase_mma<1, 0>(a1, b0, acc);                                       \
        BARRIER(); SBAR();                                                  \
        /* P4: no reads ; stage A1(t+1) */                                  \
        if (DN) { gA(sA[1][0], (BUF) ^ 1, 1, 0); gA(sA[1][1], (BUF) ^ 1, 1, 1); } \
        phase_mma<1, 1>(a1, b1, acc);                                       \
        if (DOEND) {                                                        \
            VMW(W3);                                                        \
            BARRIER(); SBAR();                                              \
        }                                                                   \
    }

    for (int t2 = 0; t2 < NKT - 2; t2 += 2) {
        KTILE(0, 1, 4, 4, 4, 1);
        KTILE(1, 1, 4, 4, 4, 1);
    }
    KTILE(0, 1, 4, 4, 4, 1);  // tile NKT-2: stages tile NKT-1 normally
    KTILE(1, 0, 2, 0, 0, 0);  // tile NKT-1: no stages; VMW 2/0; no end sync
#undef KTILE

    // Epilogue: D map col=lane&15, row=(lane>>4)*4+j (m89-verified).
    const int lrow = (lane >> 4) * 4;
    #pragma unroll
    for (int mf = 0; mf < 8; ++mf)
        #pragma unroll
        for (int nf = 0; nf < 4; ++nf)
            #pragma unroll
            for (int j = 0; j < 4; ++j) {
                const int r = row0 + (mf >> 2) * 128 + wr * 64 + (mf & 3) * 16 + lrow + j;
                const int c = col0 + (nf >> 1) * 128 + wc * 32 + (nf & 1) * 16 + l15;
                C[(size_t)r * N_ + c] = acc[mf][nf][j];
            }
}

// ---------------- Fallback: round-1 fused kernel ----------------
static constexpr int LDSS = 40;

__global__ __launch_bounds__(256, 2) void w4_gemm_fused(
    const float* __restrict__ X, const int* __restrict__ Q,
    const float* __restrict__ SZ, float* __restrict__ C) {
    __shared__ alignas(16) unsigned short As[128 * LDSS];
    __shared__ alignas(16) unsigned short Ws[128 * LDSS];
    const int tid = threadIdx.x;
    const int lane = tid & 63;
    const int wid = tid >> 6;
    const int wrr = wid >> 1;
    const int wcc = wid & 1;
    const int row0 = blockIdx.x * 128;
    const int col0 = blockIdx.y * 128;
    float4v acc[4][4] = {};
    float4v a_reg[4];
    int4v q_reg[4];
    float2v sz_reg[4];

    auto load_tile = [&](int kb) {
        const int g = kb >> 7;
        #pragma unroll
        for (int i = 0; i < 4; ++i) {
            const int idx = tid + 256 * i;
            const int r = idx >> 3;
            const int v = idx & 7;
            a_reg[i] = *(const float4v*)(X + (size_t)(row0 + r) * K_ + kb + v * 4);
            q_reg[i] = *(const int4v*)(Q + (size_t)(col0 + r) * K_ + kb + v * 4);
            sz_reg[i] = *(const float2v*)(SZ + ((size_t)g * N_ + (col0 + r)) * 2);
        }
    };
    auto write_tile = [&]() {
        #pragma unroll
        for (int i = 0; i < 4; ++i) {
            const int idx = tid + 256 * i;
            const int r = idx >> 3;
            const int v = idx & 7;
            ushort4v ab, wb;
            #pragma unroll
            for (int j = 0; j < 4; ++j) ab[j] = f2bf(a_reg[i][j]);
            const float s = sz_reg[i][0];
            const float z = sz_reg[i][1];
            #pragma unroll
            for (int j = 0; j < 4; ++j) wb[j] = f2bf((float)(q_reg[i][j] - 8) * s + z);
            *(ushort4v*)(&As[r * LDSS + v * 4]) = ab;
            *(ushort4v*)(&Ws[r * LDSS + v * 4]) = wb;
        }
    };
    auto compute = [&]() {
        const int lr = lane & 15;
        const int lg = lane >> 4;
        short8 af[4], bf[4];
        #pragma unroll
        for (int mf = 0; mf < 4; ++mf)
            af[mf] = *(const short8*)(&As[(wrr * 64 + mf * 16 + lr) * LDSS + lg * 8]);
        #pragma unroll
        for (int nf = 0; nf < 4; ++nf)
            bf[nf] = *(const short8*)(&Ws[(wcc * 64 + nf * 16 + lr) * LDSS + lg * 8]);
        #pragma unroll
        for (int mf = 0; mf < 4; ++mf)
            #pragma unroll
            for (int nf = 0; nf < 4; ++nf)
                acc[mf][nf] = __builtin_amdgcn_mfma_f32_16x16x32_bf16(
                    af[mf], bf[nf], acc[mf][nf], 0, 0, 0);
    };

    load_tile(0);
    for (int kb = 0; kb < K_; kb += 32) {
        __syncthreads();
        write_tile();
        __syncthreads();
        if (kb + 32 < K_) load_tile(kb + 32);
        compute();
    }
    const int lr = lane & 15;
    const int lg = lane >> 4;
    #pragma unroll
    for (int mf = 0; mf < 4; ++mf)
        #pragma unroll
        for (int nf = 0; nf < 4; ++nf)
            #pragma unroll
            for (int j = 0; j < 4; ++j) {
                const int r = row0 + wrr * 64 + mf * 16 + lg * 4 + j;
                const int c = col0 + wcc * 64 + nf * 16 + lr;
                C[(size_t)r * N_ + c] = acc[mf][nf][j];
            }
}

extern "C" void kernel_launch(void* const* d_in, const int* in_sizes, int n_in,
                              void* d_out, int out_size, void* d_ws, size_t ws_size,
                              hipStream_t stream) {
    const float* X  = (const float*)d_in[0];
    const int*   Q  = (const int*)d_in[1];
    const float* SZ = (const float*)d_in[2];
    float* C = (float*)d_out;

    const size_t xb_bytes = (size_t)M_ * K_ * 2;
    const size_t wb_bytes = (size_t)N_ * K_ * 2;
    if (ws_size >= xb_bytes + wb_bytes) {
        unsigned short* Xb = (unsigned short*)d_ws;
        unsigned short* Wb = (unsigned short*)((char*)d_ws + xb_bytes);
        cvt_x_kernel<<<(M_ * (K_ / 8)) / 256, 256, 0, stream>>>(X, Xb);
        deq_w_kernel<<<(N_ * (K_ / 8)) / 256, 256, 0, stream>>>(Q, SZ, Wb);
        gemm_bf16_8ph<<<dim3(1376), dim3(512), 0, stream>>>(Xb, Wb, C);
    } else {
        dim3 grid(M_ / 128, N_ / 128);
        w4_gemm_fused<<<grid, dim3(256), 0, stream>>>(X, Q, SZ, C);
    }
}